// Round 1
// baseline (608.998 us; speedup 1.0000x reference)
//
#include <hip/hip_runtime.h>
#include <hip/hip_bf16.h>

// Problem constants (fixed by the reference: B=4, S=2048, D_IN=D_OUT=4096)
#define GM 8192
#define GN 4096
#define GK 4096

// Workspace layout (bytes)
#define QX_OFF   0ull                      // int8 [8192][4096]  = 33.5 MB
#define QW_OFF   33554432ull               // int8 [4096][4096]  = 16.8 MB
#define RSX_OFF  50331648ull               // int32[8192]
#define RSW_OFF  50364416ull               // int32[4096]
#define ATOM_OFF 50380800ull               // 4 x uint encoded min/max slots
#define PRM_OFF  50380832ull               // params: sx, zxf, sw, zwf, sxsw, zxi, zwi

using v4i = __attribute__((ext_vector_type(4))) int;

// ---------- helpers ----------
__device__ __forceinline__ unsigned encf(float x) {
    unsigned u = __float_as_uint(x);
    return (u & 0x80000000u) ? ~u : (u | 0x80000000u);
}
__device__ __forceinline__ float decf(unsigned e) {
    unsigned u = (e & 0x80000000u) ? (e & 0x7FFFFFFFu) : ~e;
    return __uint_as_float(u);
}

__device__ __forceinline__ void async16(const signed char* g, signed char* l) {
    // 16B per lane, LDS dest = wave-uniform base + lane*16
    __builtin_amdgcn_global_load_lds((const __attribute__((address_space(1))) void*)g,
                                     (__attribute__((address_space(3))) void*)l,
                                     16, 0, 0);
}

// ---------- kernels ----------
__global__ void k_init(unsigned* slots) {
    if (threadIdx.x < 4) slots[threadIdx.x] = 0u;   // 0 = smallest encoded value
}

__global__ void k_minmax(const float4* __restrict__ p, int n4, unsigned* slots) {
    unsigned mx = 0u, nm = 0u;  // encoded max(x), encoded max(-x)
    for (int i = blockIdx.x * blockDim.x + threadIdx.x; i < n4;
         i += gridDim.x * blockDim.x) {
        float4 v = p[i];
        mx = max(mx, encf(v.x)); nm = max(nm, encf(-v.x));
        mx = max(mx, encf(v.y)); nm = max(nm, encf(-v.y));
        mx = max(mx, encf(v.z)); nm = max(nm, encf(-v.z));
        mx = max(mx, encf(v.w)); nm = max(nm, encf(-v.w));
    }
    #pragma unroll
    for (int o = 32; o > 0; o >>= 1) {
        mx = max(mx, (unsigned)__shfl_down((int)mx, o));
        nm = max(nm, (unsigned)__shfl_down((int)nm, o));
    }
    __shared__ unsigned smx[4], snm[4];
    int w = threadIdx.x >> 6;
    if ((threadIdx.x & 63) == 0) { smx[w] = mx; snm[w] = nm; }
    __syncthreads();
    if (threadIdx.x == 0) {
        #pragma unroll
        for (int i = 1; i < 4; i++) { mx = max(mx, smx[i]); nm = max(nm, snm[i]); }
        atomicMax(&slots[0], mx);
        atomicMax(&slots[1], nm);
    }
}

__global__ void k_params(const unsigned* __restrict__ slots, float* prm) {
    if (threadIdx.x == 0) {
        float mxx = decf(slots[0]), mnx = -decf(slots[1]);
        float sx  = (mxx - mnx) / 255.0f;
        float zxf = rintf(-128.0f - mnx / sx);
        float mxw = decf(slots[2]), mnw = -decf(slots[3]);
        float sw  = (mxw - mnw) / 255.0f;
        float zwf = rintf(-128.0f - mnw / sw);
        prm[0] = sx; prm[1] = zxf; prm[2] = sw; prm[3] = zwf; prm[4] = sx * sw;
        int* ip = (int*)prm;
        ip[5] = (int)zxf; ip[6] = (int)zwf;
    }
}

// One block (256 threads) per row of 4096 floats; quantize + row sum.
__global__ void k_quant(const float* __restrict__ src, signed char* __restrict__ q,
                        int* __restrict__ rowsum, const float* __restrict__ prm,
                        int pidx) {
    const int row = blockIdx.x, t = threadIdx.x;
    const float s  = prm[pidx];
    const float zp = prm[pidx + 1];
    const float4* srow = (const float4*)(src + (size_t)row * GK);
    int* qrow = (int*)(q + (size_t)row * GK);
    int acc = 0;
    #pragma unroll
    for (int i = 0; i < 4; i++) {
        float4 v = srow[i * 256 + t];
        int q0 = (int)fminf(fmaxf(rintf(v.x / s) + zp, -128.0f), 127.0f);
        int q1 = (int)fminf(fmaxf(rintf(v.y / s) + zp, -128.0f), 127.0f);
        int q2 = (int)fminf(fmaxf(rintf(v.z / s) + zp, -128.0f), 127.0f);
        int q3 = (int)fminf(fmaxf(rintf(v.w / s) + zp, -128.0f), 127.0f);
        acc += q0 + q1 + q2 + q3;
        qrow[i * 256 + t] = (q0 & 255) | ((q1 & 255) << 8) | ((q2 & 255) << 16)
                          | ((q3 & 255) << 24);
    }
    #pragma unroll
    for (int o = 32; o > 0; o >>= 1) acc += __shfl_down(acc, o);
    __shared__ int sa[4];
    if ((t & 63) == 0) sa[t >> 6] = acc;
    __syncthreads();
    if (t == 0) rowsum[row] = sa[0] + sa[1] + sa[2] + sa[3];
}

// 128x128 C-tile per block, BK=64. 4 waves, each owns a 64x64 quadrant as a
// 4x4 grid of 16x16x64 i8 MFMAs. A=qx [M,K] rm, B=qw [N,K] rm (BT gemm).
__global__ __launch_bounds__(256) void k_gemm(
    const signed char* __restrict__ qx, const signed char* __restrict__ qw,
    const int* __restrict__ rsx, const int* __restrict__ rsw,
    const float* __restrict__ bias, const float* __restrict__ prm,
    float* __restrict__ out) {
    __shared__ __align__(16) signed char lA[128 * 64];
    __shared__ __align__(16) signed char lB[128 * 64];

    const int tid  = threadIdx.x;
    const int lane = tid & 63;
    const int w    = tid >> 6;
    const int bid  = blockIdx.x;
    const int tm0  = (bid >> 5) * 128;   // 64 M-tiles
    const int tn0  = (bid & 31) * 128;   // 32 N-tiles

    // staging: wave w covers rows [w*32, w*32+32) of each 128x64 tile,
    // two 1KB async calls (j=0,1), lane l -> base + l*16 (contiguous layout)
    const int srow   = lane >> 2;          // 0..15
    const int schunk = (lane & 3) * 16;    // byte offset within 64B k-slice
    const signed char* gA = qx + (size_t)(tm0 + w * 32 + srow) * GK + schunk;
    const signed char* gB = qw + (size_t)(tn0 + w * 32 + srow) * GK + schunk;
    signed char* lAw = lA + w * 2048;
    signed char* lBw = lB + w * 2048;

    const int wm = (w >> 1) * 64;   // wave quadrant
    const int wn = (w & 1) * 64;
    const int fr = lane & 15;          // fragment row
    const int fk = (lane >> 4) * 16;   // fragment k byte offset

    v4i acc[4][4] = {};

    for (int k0 = 0; k0 < GK; k0 += 64) {
        #pragma unroll
        for (int j = 0; j < 2; j++) {
            async16(gA + (size_t)j * 16 * GK + k0, lAw + j * 1024);
            async16(gB + (size_t)j * 16 * GK + k0, lBw + j * 1024);
        }
        __syncthreads();   // drains vmcnt (global_load_lds) + barrier

        v4i af[4], bf[4];
        #pragma unroll
        for (int i = 0; i < 4; i++) {
            af[i] = *(const v4i*)(lA + (wm + i * 16 + fr) * 64 + fk);
            bf[i] = *(const v4i*)(lB + (wn + i * 16 + fr) * 64 + fk);
        }
        #pragma unroll
        for (int i = 0; i < 4; i++)
            #pragma unroll
            for (int j = 0; j < 4; j++)
                acc[i][j] = __builtin_amdgcn_mfma_i32_16x16x64_i8(af[i], bf[j],
                                                                  acc[i][j], 0, 0, 0);
        __syncthreads();
    }

    // epilogue: acc - zw*rowsum_x[m] - zx*rowsum_w[n] + K*zx*zw, scale, +bias
    const float sxsw = prm[4];
    const int* ip = (const int*)prm;
    const int zxi = ip[5], zwi = ip[6];
    const int kzz = GK * zxi * zwi;
    const int q4 = (lane >> 4) * 4;
    #pragma unroll
    for (int i = 0; i < 4; i++) {
        #pragma unroll
        for (int j = 0; j < 4; j++) {
            const int col = tn0 + wn + j * 16 + fr;   // C/D: col = lane&15
            const int rw  = rsw[col];
            const float bv = bias[col];
            #pragma unroll
            for (int r = 0; r < 4; r++) {
                const int row = tm0 + wm + i * 16 + q4 + r;  // row = quad*4+reg
                const int t = acc[i][j][r] - zwi * rsx[row] - zxi * rw + kzz;
                out[(size_t)row * GN + col] = fmaf(sxsw, (float)t, bv);
            }
        }
    }
}

// ---------- launch ----------
extern "C" void kernel_launch(void* const* d_in, const int* in_sizes, int n_in,
                              void* d_out, int out_size, void* d_ws, size_t ws_size,
                              hipStream_t stream) {
    const float* x    = (const float*)d_in[0];
    const float* Wt   = (const float*)d_in[1];
    const float* bias = (const float*)d_in[2];
    float* out = (float*)d_out;

    char* ws = (char*)d_ws;
    signed char* qx = (signed char*)(ws + QX_OFF);
    signed char* qw = (signed char*)(ws + QW_OFF);
    int* rsx = (int*)(ws + RSX_OFF);
    int* rsw = (int*)(ws + RSW_OFF);
    unsigned* slots = (unsigned*)(ws + ATOM_OFF);
    float* prm = (float*)(ws + PRM_OFF);

    k_init<<<1, 64, 0, stream>>>(slots);
    k_minmax<<<4096, 256, 0, stream>>>((const float4*)x,  GM * GK / 4, slots);
    k_minmax<<<2048, 256, 0, stream>>>((const float4*)Wt, GN * GK / 4, slots + 2);
    k_params<<<1, 1, 0, stream>>>(slots, prm);
    k_quant<<<GM, 256, 0, stream>>>(x,  qx, rsx, prm, 0);
    k_quant<<<GN, 256, 0, stream>>>(Wt, qw, rsw, prm, 2);
    k_gemm<<<(GM / 128) * (GN / 128), 256, 0, stream>>>(qx, qw, rsx, rsw, bias,
                                                        prm, out);
}

// Round 2
// 559.409 us; speedup vs baseline: 1.0886x; 1.0886x over previous
//
#include <hip/hip_runtime.h>
#include <hip/hip_bf16.h>

// Problem constants (fixed by the reference: B=4, S=2048, D_IN=D_OUT=4096)
#define GM 8192
#define GN 4096
#define GK 4096

// Workspace layout (bytes)
#define QX_OFF   0ull                      // int8 [8192][4096]  = 33.5 MB
#define QW_OFF   33554432ull               // int8 [4096][4096]  = 16.8 MB
#define RSX_OFF  50331648ull               // int32[8192]
#define RSW_OFF  50364416ull               // int32[4096]
#define ATOM_OFF 50380800ull               // 4 x uint encoded min/max slots
#define PRM_OFF  50380832ull               // params: sx, zxf, sw, zwf, sxsw, zxi, zwi

using v4i  = __attribute__((ext_vector_type(4)))  int;
using v16i = __attribute__((ext_vector_type(16))) int;

// ---------- helpers ----------
__device__ __forceinline__ unsigned encf(float x) {
    unsigned u = __float_as_uint(x);
    return (u & 0x80000000u) ? ~u : (u | 0x80000000u);
}
__device__ __forceinline__ float decf(unsigned e) {
    unsigned u = (e & 0x80000000u) ? (e & 0x7FFFFFFFu) : ~e;
    return __uint_as_float(u);
}

__device__ __forceinline__ void async16(const signed char* g, signed char* l) {
    // 16B per lane, LDS dest = wave-uniform base + lane*16 (m104/m108 rule)
    __builtin_amdgcn_global_load_lds((const __attribute__((address_space(1))) void*)g,
                                     (__attribute__((address_space(3))) void*)l,
                                     16, 0, 0);
}

// ---------- kernels ----------
__global__ void k_init(unsigned* slots) {
    if (threadIdx.x < 4) slots[threadIdx.x] = 0u;   // 0 = smallest encoded value
}

// blocks [0,4096) -> x (slots 0,1);  [4096,6144) -> W (slots 2,3)
__global__ void k_minmax(const float4* __restrict__ x, const float4* __restrict__ Wt,
                         unsigned* slots) {
    const float4* p; int n4, b0, nb; unsigned* sl;
    if (blockIdx.x < 4096) { p = x;  n4 = GM * GK / 4; b0 = blockIdx.x;        nb = 4096; sl = slots;     }
    else                   { p = Wt; n4 = GN * GK / 4; b0 = blockIdx.x - 4096; nb = 2048; sl = slots + 2; }
    unsigned mx = 0u, nm = 0u;  // encoded max(x), encoded max(-x)
    for (int i = b0 * 256 + threadIdx.x; i < n4; i += nb * 256) {
        float4 v = p[i];
        mx = max(mx, encf(v.x)); nm = max(nm, encf(-v.x));
        mx = max(mx, encf(v.y)); nm = max(nm, encf(-v.y));
        mx = max(mx, encf(v.z)); nm = max(nm, encf(-v.z));
        mx = max(mx, encf(v.w)); nm = max(nm, encf(-v.w));
    }
    #pragma unroll
    for (int o = 32; o > 0; o >>= 1) {
        mx = max(mx, (unsigned)__shfl_down((int)mx, o));
        nm = max(nm, (unsigned)__shfl_down((int)nm, o));
    }
    __shared__ unsigned smx[4], snm[4];
    int w = threadIdx.x >> 6;
    if ((threadIdx.x & 63) == 0) { smx[w] = mx; snm[w] = nm; }
    __syncthreads();
    if (threadIdx.x == 0) {
        #pragma unroll
        for (int i = 1; i < 4; i++) { mx = max(mx, smx[i]); nm = max(nm, snm[i]); }
        atomicMax(&sl[0], mx);
        atomicMax(&sl[1], nm);
    }
}

__global__ void k_params(const unsigned* __restrict__ slots, float* prm) {
    if (threadIdx.x == 0) {
        float mxx = decf(slots[0]), mnx = -decf(slots[1]);
        float sx  = (mxx - mnx) / 255.0f;
        float zxf = rintf(-128.0f - mnx / sx);
        float mxw = decf(slots[2]), mnw = -decf(slots[3]);
        float sw  = (mxw - mnw) / 255.0f;
        float zwf = rintf(-128.0f - mnw / sw);
        prm[0] = sx; prm[1] = zxf; prm[2] = sw; prm[3] = zwf; prm[4] = sx * sw;
        int* ip = (int*)prm;
        ip[5] = (int)zxf; ip[6] = (int)zwf;
    }
}

// One block (256 threads) per row of 4096 floats; quantize + row sum.
// blocks [0,GM) -> x rows; [GM, GM+GN) -> W rows.
__global__ void k_quant(const float* __restrict__ x, const float* __restrict__ Wt,
                        signed char* __restrict__ qx, signed char* __restrict__ qw,
                        int* __restrict__ rsx, int* __restrict__ rsw,
                        const float* __restrict__ prm) {
    const float* src; signed char* q; int* rs; int pidx, row;
    if (blockIdx.x < GM) { row = blockIdx.x;      src = x;  q = qx; rs = rsx; pidx = 0; }
    else                 { row = blockIdx.x - GM; src = Wt; q = qw; rs = rsw; pidx = 2; }
    const int t = threadIdx.x;
    const float s  = prm[pidx];
    const float zp = prm[pidx + 1];
    const float4* srow = (const float4*)(src + (size_t)row * GK);
    int* qrow = (int*)(q + (size_t)row * GK);
    int acc = 0;
    #pragma unroll
    for (int i = 0; i < 4; i++) {
        float4 v = srow[i * 256 + t];
        int q0 = (int)fminf(fmaxf(rintf(v.x / s) + zp, -128.0f), 127.0f);
        int q1 = (int)fminf(fmaxf(rintf(v.y / s) + zp, -128.0f), 127.0f);
        int q2 = (int)fminf(fmaxf(rintf(v.z / s) + zp, -128.0f), 127.0f);
        int q3 = (int)fminf(fmaxf(rintf(v.w / s) + zp, -128.0f), 127.0f);
        acc += q0 + q1 + q2 + q3;
        qrow[i * 256 + t] = (q0 & 255) | ((q1 & 255) << 8) | ((q2 & 255) << 16)
                          | ((q3 & 255) << 24);
    }
    #pragma unroll
    for (int o = 32; o > 0; o >>= 1) acc += __shfl_down(acc, o);
    __shared__ int sa[4];
    if ((t & 63) == 0) sa[t >> 6] = acc;
    __syncthreads();
    if (t == 0) rs[row] = sa[0] + sa[1] + sa[2] + sa[3];
}

// 128x128 C-tile per block, BK=128. 4 waves, each owns a 64x64 quadrant as a
// 2x2 grid of 32x32x32 i8 MFMAs. A=qx [M,K] rm, B=qw [N,K] rm (BT gemm).
// LDS layout XOR-swizzled: chunk c (16B) of row r lives at r*128 + (c^(r&7))*16,
// so frag reads spread 32-lane row-groups across all 8 bank-quads.
__global__ __launch_bounds__(256) void k_gemm(
    const signed char* __restrict__ qx, const signed char* __restrict__ qw,
    const int* __restrict__ rsx, const int* __restrict__ rsw,
    const float* __restrict__ bias, const float* __restrict__ prm,
    float* __restrict__ out) {
    __shared__ __align__(16) signed char lA[128 * 128];
    __shared__ __align__(16) signed char lB[128 * 128];

    const int tid  = threadIdx.x;
    const int lane = tid & 63;
    const int w    = tid >> 6;
    const int bid  = blockIdx.x;
    const int tm0  = (bid >> 5) * 128;   // 64 M-tiles
    const int tn0  = (bid & 31) * 128;   // 32 N-tiles

    // staging: wave w covers rows [w*32, w*32+32) of each 128x128B tile.
    // 4 async16 calls/wave/tile, each 1 KB = 8 rows. Lane l -> LDS base + l*16,
    // which holds (row = j*8 + (l>>3), chunk c = (l&7) ^ (l>>3)) of the slab.
    const int sr = lane >> 3;              // row within 8-row group
    const int sc = ((lane & 7) ^ sr) * 16; // swizzled source chunk byte offset
    const signed char* gA = qx + (size_t)(tm0 + w * 32 + sr) * GK + sc;
    const signed char* gB = qw + (size_t)(tn0 + w * 32 + sr) * GK + sc;
    signed char* lAw = lA + w * 4096;
    signed char* lBw = lB + w * 4096;

    const int wm = (w >> 1) * 64;   // wave quadrant
    const int wn = (w & 1) * 64;
    const int fr = lane & 31;       // A row / B col within 32-block
    const int fh = lane >> 5;       // k-half selector (16B of the 32B k-slice)

    v16i acc[2][2] = {};

    for (int k0 = 0; k0 < GK; k0 += 128) {
        #pragma unroll
        for (int j = 0; j < 4; j++) {
            async16(gA + (size_t)j * 8 * GK + k0, lAw + j * 1024);
            async16(gB + (size_t)j * 8 * GK + k0, lBw + j * 1024);
        }
        __syncthreads();   // drains vmcnt (global_load_lds) + barrier

        #pragma unroll
        for (int s = 0; s < 4; s++) {
            const int ca = ((s * 2 + fh) ^ (lane & 7)) * 16;  // swizzled chunk
            v4i a0 = *(const v4i*)(lA + (wm      + fr) * 128 + ca);
            v4i a1 = *(const v4i*)(lA + (wm + 32 + fr) * 128 + ca);
            v4i b0 = *(const v4i*)(lB + (wn      + fr) * 128 + ca);
            v4i b1 = *(const v4i*)(lB + (wn + 32 + fr) * 128 + ca);
            acc[0][0] = __builtin_amdgcn_mfma_i32_32x32x32_i8(a0, b0, acc[0][0], 0, 0, 0);
            acc[0][1] = __builtin_amdgcn_mfma_i32_32x32x32_i8(a0, b1, acc[0][1], 0, 0, 0);
            acc[1][0] = __builtin_amdgcn_mfma_i32_32x32x32_i8(a1, b0, acc[1][0], 0, 0, 0);
            acc[1][1] = __builtin_amdgcn_mfma_i32_32x32x32_i8(a1, b1, acc[1][1], 0, 0, 0);
        }
        __syncthreads();
    }

    // epilogue: acc - zw*rowsum_x[m] - zx*rowsum_w[n] + K*zx*zw, scale, +bias
    // 32x32 C/D: col = lane&31, row = (reg&3) + 8*(reg>>2) + 4*(lane>>5)
    const float sxsw = prm[4];
    const int* ip = (const int*)prm;
    const int zxi = ip[5], zwi = ip[6];
    const int kzz = GK * zxi * zwi;
    #pragma unroll
    for (int i = 0; i < 2; i++) {
        #pragma unroll
        for (int j = 0; j < 2; j++) {
            const int col = tn0 + wn + j * 32 + fr;
            const int ccol = kzz - zxi * rsw[col];
            const float bv = bias[col];
            #pragma unroll
            for (int reg = 0; reg < 16; reg++) {
                const int row = tm0 + wm + i * 32 + (reg & 3) + 8 * (reg >> 2) + 4 * fh;
                const int t = acc[i][j][reg] - zwi * rsx[row] + ccol;
                out[(size_t)row * GN + col] = fmaf(sxsw, (float)t, bv);
            }
        }
    }
}

// ---------- launch ----------
extern "C" void kernel_launch(void* const* d_in, const int* in_sizes, int n_in,
                              void* d_out, int out_size, void* d_ws, size_t ws_size,
                              hipStream_t stream) {
    const float* x    = (const float*)d_in[0];
    const float* Wt   = (const float*)d_in[1];
    const float* bias = (const float*)d_in[2];
    float* out = (float*)d_out;

    char* ws = (char*)d_ws;
    signed char* qx = (signed char*)(ws + QX_OFF);
    signed char* qw = (signed char*)(ws + QW_OFF);
    int* rsx = (int*)(ws + RSX_OFF);
    int* rsw = (int*)(ws + RSW_OFF);
    unsigned* slots = (unsigned*)(ws + ATOM_OFF);
    float* prm = (float*)(ws + PRM_OFF);

    k_init<<<1, 64, 0, stream>>>(slots);
    k_minmax<<<6144, 256, 0, stream>>>((const float4*)x, (const float4*)Wt, slots);
    k_params<<<1, 1, 0, stream>>>(slots, prm);
    k_quant<<<GM + GN, 256, 0, stream>>>(x, Wt, qx, qw, rsx, rsw, prm);
    k_gemm<<<(GM / 128) * (GN / 128), 256, 0, stream>>>(qx, qw, rsx, rsw, bias,
                                                        prm, out);
}

// Round 3
// 530.101 us; speedup vs baseline: 1.1488x; 1.0553x over previous
//
#include <hip/hip_runtime.h>
#include <hip/hip_bf16.h>

// Problem constants (fixed by the reference: B=4, S=2048, D_IN=D_OUT=4096)
#define GM 8192
#define GN 4096
#define GK 4096

// Workspace layout (bytes)
#define QX_OFF   0ull                      // int8 [8192][4096]  = 33.5 MB
#define QW_OFF   33554432ull               // int8 [4096][4096]  = 16.8 MB
#define RSX_OFF  50331648ull               // int32[8192]
#define RSW_OFF  50364416ull               // int32[4096]
#define ATOM_OFF 50380800ull               // 4 x uint encoded min/max slots
#define PRM_OFF  50380832ull               // params: sx, zxf, sw, zwf, sxsw, zxi, zwi

using v4i  = __attribute__((ext_vector_type(4)))  int;
using v16i = __attribute__((ext_vector_type(16))) int;

// ---------- helpers ----------
__device__ __forceinline__ unsigned encf(float x) {
    unsigned u = __float_as_uint(x);
    return (u & 0x80000000u) ? ~u : (u | 0x80000000u);
}
__device__ __forceinline__ float decf(unsigned e) {
    unsigned u = (e & 0x80000000u) ? (e & 0x7FFFFFFFu) : ~e;
    return __uint_as_float(u);
}

__device__ __forceinline__ void async16(const signed char* g, signed char* l) {
    // 16B per lane, LDS dest = wave-uniform base + lane*16 (m104/m108 rule)
    __builtin_amdgcn_global_load_lds((const __attribute__((address_space(1))) void*)g,
                                     (__attribute__((address_space(3))) void*)l,
                                     16, 0, 0);
}

// ---------- kernels ----------
__global__ void k_init(unsigned* slots) {
    if (threadIdx.x < 4) slots[threadIdx.x] = 0u;   // 0 = smallest encoded value
}

// blocks [0,4096) -> x (slots 0,1);  [4096,6144) -> W (slots 2,3)
__global__ void k_minmax(const float4* __restrict__ x, const float4* __restrict__ Wt,
                         unsigned* slots) {
    const float4* p; int n4, b0, nb; unsigned* sl;
    if (blockIdx.x < 4096) { p = x;  n4 = GM * GK / 4; b0 = blockIdx.x;        nb = 4096; sl = slots;     }
    else                   { p = Wt; n4 = GN * GK / 4; b0 = blockIdx.x - 4096; nb = 2048; sl = slots + 2; }
    unsigned mx = 0u, nm = 0u;  // encoded max(x), encoded max(-x)
    for (int i = b0 * 256 + threadIdx.x; i < n4; i += nb * 256) {
        float4 v = p[i];
        mx = max(mx, encf(v.x)); nm = max(nm, encf(-v.x));
        mx = max(mx, encf(v.y)); nm = max(nm, encf(-v.y));
        mx = max(mx, encf(v.z)); nm = max(nm, encf(-v.z));
        mx = max(mx, encf(v.w)); nm = max(nm, encf(-v.w));
    }
    #pragma unroll
    for (int o = 32; o > 0; o >>= 1) {
        mx = max(mx, (unsigned)__shfl_down((int)mx, o));
        nm = max(nm, (unsigned)__shfl_down((int)nm, o));
    }
    __shared__ unsigned smx[4], snm[4];
    int w = threadIdx.x >> 6;
    if ((threadIdx.x & 63) == 0) { smx[w] = mx; snm[w] = nm; }
    __syncthreads();
    if (threadIdx.x == 0) {
        #pragma unroll
        for (int i = 1; i < 4; i++) { mx = max(mx, smx[i]); nm = max(nm, snm[i]); }
        atomicMax(&sl[0], mx);
        atomicMax(&sl[1], nm);
    }
}

__global__ void k_params(const unsigned* __restrict__ slots, float* prm) {
    if (threadIdx.x == 0) {
        float mxx = decf(slots[0]), mnx = -decf(slots[1]);
        float sx  = (mxx - mnx) / 255.0f;
        float zxf = rintf(-128.0f - mnx / sx);
        float mxw = decf(slots[2]), mnw = -decf(slots[3]);
        float sw  = (mxw - mnw) / 255.0f;
        float zwf = rintf(-128.0f - mnw / sw);
        prm[0] = sx; prm[1] = zxf; prm[2] = sw; prm[3] = zwf; prm[4] = sx * sw;
        int* ip = (int*)prm;
        ip[5] = (int)zxf; ip[6] = (int)zwf;
    }
}

// One block (256 threads) per row of 4096 floats; quantize + row sum.
// blocks [0,GM) -> x rows; [GM, GM+GN) -> W rows.
__global__ void k_quant(const float* __restrict__ x, const float* __restrict__ Wt,
                        signed char* __restrict__ qx, signed char* __restrict__ qw,
                        int* __restrict__ rsx, int* __restrict__ rsw,
                        const float* __restrict__ prm) {
    const float* src; signed char* q; int* rs; int pidx, row;
    if (blockIdx.x < GM) { row = blockIdx.x;      src = x;  q = qx; rs = rsx; pidx = 0; }
    else                 { row = blockIdx.x - GM; src = Wt; q = qw; rs = rsw; pidx = 2; }
    const int t = threadIdx.x;
    const float s  = prm[pidx];
    const float zp = prm[pidx + 1];
    const float4* srow = (const float4*)(src + (size_t)row * GK);
    int* qrow = (int*)(q + (size_t)row * GK);
    int acc = 0;
    #pragma unroll
    for (int i = 0; i < 4; i++) {
        float4 v = srow[i * 256 + t];
        int q0 = (int)fminf(fmaxf(rintf(v.x / s) + zp, -128.0f), 127.0f);
        int q1 = (int)fminf(fmaxf(rintf(v.y / s) + zp, -128.0f), 127.0f);
        int q2 = (int)fminf(fmaxf(rintf(v.z / s) + zp, -128.0f), 127.0f);
        int q3 = (int)fminf(fmaxf(rintf(v.w / s) + zp, -128.0f), 127.0f);
        acc += q0 + q1 + q2 + q3;
        qrow[i * 256 + t] = (q0 & 255) | ((q1 & 255) << 8) | ((q2 & 255) << 16)
                          | ((q3 & 255) << 24);
    }
    #pragma unroll
    for (int o = 32; o > 0; o >>= 1) acc += __shfl_down(acc, o);
    __shared__ int sa[4];
    if ((t & 63) == 0) sa[t >> 6] = acc;
    __syncthreads();
    if (t == 0) rs[row] = sa[0] + sa[1] + sa[2] + sa[3];
}

// 256x256 C-tile per block, BK=64, double-buffered LDS (2 x 32 KB).
// 8 waves (512 thr) in a 2(M) x 4(N) grid of 128x64 wave-tiles; each wave:
// 4x2 grid of 32x32x32 i8 MFMAs -> reads/MFMA = 0.75 (vs 1.0 in r2) and
// staged-LDS bytes halved. A=qx [M,K] rm, B=qw [N,K] rm (BT gemm).
// LDS rows are 64B; chunk c (16B) of row r stored at pos (c ^ (r&3)) -> frag
// reads land as 2-way bank aliases only (free per m136).
__global__ __launch_bounds__(512, 2) void k_gemm(
    const signed char* __restrict__ qx, const signed char* __restrict__ qw,
    const int* __restrict__ rsx, const int* __restrict__ rsw,
    const float* __restrict__ bias, const float* __restrict__ prm,
    float* __restrict__ out) {
    __shared__ __align__(16) signed char lds[2][2][256 * 64];  // [buf][A/B] = 64 KB

    const int tid  = threadIdx.x;
    const int lane = tid & 63;
    const int w    = tid >> 6;          // 0..7
    const int bid  = blockIdx.x;
    const int tm0  = (bid >> 4) * 256;  // 32 M-tiles
    const int tn0  = (bid & 15) * 256;  // 16 N-tiles

    // ---- staging setup: waves 0-3 -> A slab rows [w*64,+64); 4-7 -> B ----
    const int slab = w & 3;
    const int sr   = lane >> 2;                         // row 0..15 within 1KB call
    const int sc   = ((lane & 3) ^ (sr & 3)) * 16;      // swizzled source chunk
    const signed char* gsrc = (w < 4)
        ? qx + (size_t)(tm0 + slab * 64 + sr) * GK + sc
        : qw + (size_t)(tn0 + slab * 64 + sr) * GK + sc;
    const int ldsTensor = (w < 4) ? 0 : 1;
    const int ldsSlab   = slab * 64 * 64;               // byte offset of 64-row slab

    // ---- fragment / MFMA setup ----
    const int wr = w >> 2;              // 0..1 : wave row (M) position
    const int wc = w & 3;               // 0..3 : wave col (N) position
    const int fr = lane & 31;           // row within 32-block
    const int fh = lane >> 5;           // k-half selector

    v16i acc[4][2] = {};

    // stage tile 0 into buf 0
    #pragma unroll
    for (int j = 0; j < 4; j++)
        async16(gsrc + (size_t)j * 16 * GK,
                &lds[0][ldsTensor][ldsSlab + j * 1024]);
    __syncthreads();

    for (int kt = 0; kt < GK / 64; ++kt) {
        const int cur = kt & 1;
        if (kt + 1 < GK / 64) {
            const size_t ko = (size_t)(kt + 1) * 64;
            #pragma unroll
            for (int j = 0; j < 4; j++)
                async16(gsrc + (size_t)j * 16 * GK + ko,
                        &lds[cur ^ 1][ldsTensor][ldsSlab + j * 1024]);
        }
        // compute on cur while next tile's loads are in flight
        const signed char* cA = lds[cur][0];
        const signed char* cB = lds[cur][1];
        #pragma unroll
        for (int s = 0; s < 2; s++) {
            const int cc = s * 2 + fh;                  // 16B chunk index 0..3
            const int ca = (cc ^ (fr & 3)) * 16;        // swizzled pos
            v4i a0 = *(const v4i*)(cA + (wr * 128      + fr) * 64 + ca);
            v4i a1 = *(const v4i*)(cA + (wr * 128 + 32 + fr) * 64 + ca);
            v4i a2 = *(const v4i*)(cA + (wr * 128 + 64 + fr) * 64 + ca);
            v4i a3 = *(const v4i*)(cA + (wr * 128 + 96 + fr) * 64 + ca);
            v4i b0 = *(const v4i*)(cB + (wc * 64       + fr) * 64 + ca);
            v4i b1 = *(const v4i*)(cB + (wc * 64  + 32 + fr) * 64 + ca);
            acc[0][0] = __builtin_amdgcn_mfma_i32_32x32x32_i8(a0, b0, acc[0][0], 0, 0, 0);
            acc[0][1] = __builtin_amdgcn_mfma_i32_32x32x32_i8(a0, b1, acc[0][1], 0, 0, 0);
            acc[1][0] = __builtin_amdgcn_mfma_i32_32x32x32_i8(a1, b0, acc[1][0], 0, 0, 0);
            acc[1][1] = __builtin_amdgcn_mfma_i32_32x32x32_i8(a1, b1, acc[1][1], 0, 0, 0);
            acc[2][0] = __builtin_amdgcn_mfma_i32_32x32x32_i8(a2, b0, acc[2][0], 0, 0, 0);
            acc[2][1] = __builtin_amdgcn_mfma_i32_32x32x32_i8(a2, b1, acc[2][1], 0, 0, 0);
            acc[3][0] = __builtin_amdgcn_mfma_i32_32x32x32_i8(a3, b0, acc[3][0], 0, 0, 0);
            acc[3][1] = __builtin_amdgcn_mfma_i32_32x32x32_i8(a3, b1, acc[3][1], 0, 0, 0);
        }
        __syncthreads();   // drains next-tile loads (issued pre-compute) + read fence
    }

    // epilogue: acc - zw*rowsum_x[m] - zx*rowsum_w[n] + K*zx*zw, scale, +bias
    // 32x32 C/D: col = lane&31, row = (reg&3) + 8*(reg>>2) + 4*(lane>>5)
    const float sxsw = prm[4];
    const int* ip = (const int*)prm;
    const int zxi = ip[5], zwi = ip[6];
    const int kzz = GK * zxi * zwi;
    #pragma unroll
    for (int i = 0; i < 4; i++) {
        #pragma unroll
        for (int j = 0; j < 2; j++) {
            const int col = tn0 + wc * 64 + j * 32 + fr;
            const int ccol = kzz - zxi * rsw[col];
            const float bv = bias[col];
            #pragma unroll
            for (int reg = 0; reg < 16; reg++) {
                const int row = tm0 + wr * 128 + i * 32
                              + (reg & 3) + 8 * (reg >> 2) + 4 * fh;
                const int t = acc[i][j][reg] - zwi * rsx[row] + ccol;
                out[(size_t)row * GN + col] = fmaf(sxsw, (float)t, bv);
            }
        }
    }
}

// ---------- launch ----------
extern "C" void kernel_launch(void* const* d_in, const int* in_sizes, int n_in,
                              void* d_out, int out_size, void* d_ws, size_t ws_size,
                              hipStream_t stream) {
    const float* x    = (const float*)d_in[0];
    const float* Wt   = (const float*)d_in[1];
    const float* bias = (const float*)d_in[2];
    float* out = (float*)d_out;

    char* ws = (char*)d_ws;
    signed char* qx = (signed char*)(ws + QX_OFF);
    signed char* qw = (signed char*)(ws + QW_OFF);
    int* rsx = (int*)(ws + RSX_OFF);
    int* rsw = (int*)(ws + RSW_OFF);
    unsigned* slots = (unsigned*)(ws + ATOM_OFF);
    float* prm = (float*)(ws + PRM_OFF);

    k_init<<<1, 64, 0, stream>>>(slots);
    k_minmax<<<6144, 256, 0, stream>>>((const float4*)x, (const float4*)Wt, slots);
    k_params<<<1, 1, 0, stream>>>(slots, prm);
    k_quant<<<GM + GN, 256, 0, stream>>>(x, Wt, qx, qw, rsx, rsw, prm);
    k_gemm<<<(GM / 256) * (GN / 256), 512, 0, stream>>>(qx, qw, rsx, rsw, bias,
                                                        prm, out);
}